// Round 11
// baseline (28.601 us; speedup 1.0000x reference)
//
#include <hip/hip_runtime.h>
#include <math.h>

#define SS 2048
#define OSQ 512
#define GG 5

typedef unsigned short u16;
typedef unsigned int u32;
typedef __attribute__((ext_vector_type(8))) short s16x8;
typedef __attribute__((ext_vector_type(4))) float v4f;
typedef __attribute__((ext_vector_type(16))) float v16f;

__device__ __forceinline__ float rcp_f(float x) {
    float r; asm("v_rcp_f32 %0, %1" : "=v"(r) : "v"(x)); return r;
}
__device__ __forceinline__ float cos_rev(float x) {
    float fr, c;
    asm("v_fract_f32 %0, %1" : "=v"(fr) : "v"(x));
    asm("v_cos_f32 %0, %1" : "=v"(c) : "v"(fr));
    return c;
}
__device__ __forceinline__ float cos01(float x) {
    float c; asm("v_cos_f32 %0, %1" : "=v"(c) : "v"(x)); return c;
}
__device__ __forceinline__ u16 f2bf(float f) {
    u32 u = __float_as_uint(f);
    return (u16)((u + 0x7FFFu + ((u >> 16) & 1u)) >> 16);
}
__device__ __forceinline__ u32 pk2bf(float lo, float hi) {
    return (u32)f2bf(lo) | ((u32)f2bf(hi) << 16);
}
__device__ __forceinline__ float bf2f(u16 h) {
    return __uint_as_float((u32)h << 16);
}
__device__ __forceinline__ void gload16(const void* g, void* l) {
    __builtin_amdgcn_global_load_lds((const __attribute__((address_space(1))) void*)g,
                                     (__attribute__((address_space(3))) void*)l, 16, 0, 0);
}

// ---------------------------------------------------------------------------
// Fragment layouts (16B per lane-slot, bf16):
//   Lt_frag[(o32blk*128 + ks)*64 + slot] : Linker[k][o],
//       o = o32blk*32 + (slot&31), k = ks*16 + (slot>>5)*8 + {0..7}
//   Vt_frag[((b*2+i32blk)*128 + ks)*64 + slot] : V[b][i][k], same slot rule.
// A 4-k block fills the half-slot at byte offset (k0&4)*2 within each 16B slot.
// ---------------------------------------------------------------------------

// kF512: grid 512 x 512, 2 blocks/CU (35 KB LDS, <=128 VGPR via j-split).
// Per block (k0 = bid*4): Z0 = seq@M^T (MFMA), LayerNorm, W on-the-fly
// (cos recurrence, two j-half passes), T per-k (MFMA), V = T+Z0 -> Vt
// fragments; plus this k-slice of Lt.
__global__ __launch_bounds__(512, 2) void kF(const float* __restrict__ seq,
                                             const float* __restrict__ Mm,
                                             const float* __restrict__ P,
                                             const float* __restrict__ gamma,
                                             const float* __restrict__ beta,
                                             const float* __restrict__ Lnk,
                                             u16* __restrict__ Lt,
                                             u16* __restrict__ Vt) {
    __shared__ __align__(16) u16 SEQb[32 * 64];   // bf16, swizzled by (row&7)
    __shared__ __align__(16) u16 Mb[64 * 64];     // bf16, swizzled by (o&7)
    __shared__ __align__(16) u16 SZb[32 * 64];    // Z bf16, swizzled by batch
    __shared__ float Z0l[32 * 68];                // pre-LN projection, f32
    __shared__ u32 Ta32[4 * 2 * 64 * 5];          // T partials bf16 [kc][h][i][10 u16]

    const int t = threadIdx.x;
    const int l = t & 63;
    const int w = t >> 6;
    const int k0 = blockIdx.x * 4;
    const float kf0 = (float)k0;

    const int h = w >> 2;                 // j-half (coarse: j 0-31 / 32-63)
    const int i0 = (w & 3) * 16;
    const int i_w = i0 + (l & 15);
    const int jc_w = h * 4 + (l >> 4);    // 8-j chunk 0..7

    // Lt source loads: issue early, consume at end (hidden under trans init).
    float lnv[4];
    #pragma unroll
    for (int j = 0; j < 4; ++j)
        lnv[j] = Lnk[(size_t)(k0 + j) * OSQ + t];

    // stage seq rows (32 = 8b x 4kq) as bf16 (swizzled); waves 0-3 only
    if (t < 256) {
        int row = t >> 3, ch = t & 7;
        int b = row >> 2, kq = row & 3;
        const float* sp = &seq[((size_t)b * SS + k0 + kq) * 64 + ch * 8];
        float4 a = *(const float4*)sp, bb4 = *(const float4*)(sp + 4);
        uint4 pk;
        pk.x = pk2bf(a.x, a.y);
        pk.y = pk2bf(a.z, a.w);
        pk.z = pk2bf(bb4.x, bb4.y);
        pk.w = pk2bf(bb4.z, bb4.w);
        *(uint4*)&SEQb[row * 64 + ((ch ^ (row & 7)) * 8)] = pk;
    }
    // stage M (all 64 rows, all threads)
    {
        int row = t >> 3, ch = t & 7;
        const float* mp = &Mm[(size_t)row * 64 + ch * 8];
        float4 c = *(const float4*)mp, d = *(const float4*)(mp + 4);
        uint4 pm;
        pm.x = pk2bf(c.x, c.y);
        pm.y = pk2bf(c.z, c.w);
        pm.z = pk2bf(d.x, d.y);
        pm.w = pk2bf(d.z, d.w);
        *(uint4*)&Mb[row * 64 + ((ch ^ (row & 7)) * 8)] = pm;
    }

    float gm[8], bt[8];
    {
        int oc = t & 7;
        float4 a = *(const float4*)&gamma[oc * 8], b = *(const float4*)&gamma[oc * 8 + 4];
        float4 c = *(const float4*)&beta[oc * 8],  d = *(const float4*)&beta[oc * 8 + 4];
        gm[0]=a.x; gm[1]=a.y; gm[2]=a.z; gm[3]=a.w; gm[4]=b.x; gm[5]=b.y; gm[6]=b.z; gm[7]=b.w;
        bt[0]=c.x; bt[1]=c.y; bt[2]=c.z; bt[3]=c.w; bt[4]=d.x; bt[5]=d.y; bt[6]=d.z; bt[7]=d.w;
    }
    __syncthreads();

    // phase 1: Z0 (32 rows x 64 cols) via mfma_32x32x16; waves 0-1 (qc = w)
    if (w < 2) {
        v16f acc = {0,0,0,0,0,0,0,0,0,0,0,0,0,0,0,0};
        const int rowA = l & 31;
        const int rowB = w * 32 + (l & 31);
        #pragma unroll
        for (int ks = 0; ks < 4; ++ks) {
            int cA = (ks * 2 + (l >> 5)) ^ (rowA & 7);
            int cB = (ks * 2 + (l >> 5)) ^ (rowB & 7);
            s16x8 af = *(const s16x8*)&SEQb[rowA * 64 + cA * 8];
            s16x8 bf = *(const s16x8*)&Mb[rowB * 64 + cB * 8];
            acc = __builtin_amdgcn_mfma_f32_32x32x16_bf16(af, bf, acc, 0, 0, 0);
        }
        #pragma unroll
        for (int q = 0; q < 16; ++q) {
            int row = (q & 3) + 8 * (q >> 2) + 4 * (l >> 5);
            int col = w * 32 + (l & 31);
            Z0l[row * 68 + col] = acc[q];
        }
    }
    __syncthreads();

    // LayerNorm (32 rows, 8 threads/row) -> SZb bf16; waves 0-3
    if (t < 256) {
        const int rI = t >> 3, oc = t & 7;
        float z0v[8];
        float4 a = *(const float4*)&Z0l[rI * 68 + oc * 8];
        float4 b = *(const float4*)&Z0l[rI * 68 + oc * 8 + 4];
        z0v[0]=a.x; z0v[1]=a.y; z0v[2]=a.z; z0v[3]=a.w; z0v[4]=b.x; z0v[5]=b.y; z0v[6]=b.z; z0v[7]=b.w;
        float s1 = ((z0v[0]+z0v[1])+(z0v[2]+z0v[3])) + ((z0v[4]+z0v[5])+(z0v[6]+z0v[7]));
        s1 += __shfl_xor(s1, 1); s1 += __shfl_xor(s1, 2); s1 += __shfl_xor(s1, 4);
        float mu = s1 * 0.015625f;
        float sq = 0.f;
        #pragma unroll
        for (int m = 0; m < 8; ++m) { float dv = z0v[m] - mu; sq = fmaf(dv, dv, sq); }
        sq += __shfl_xor(sq, 1); sq += __shfl_xor(sq, 2); sq += __shfl_xor(sq, 4);
        float rstd = rsqrtf(sq * 0.015625f + 1e-5f);
        uint4 pk;
        pk.x = pk2bf(fmaf((z0v[0]-mu)*rstd, gm[0], bt[0]), fmaf((z0v[1]-mu)*rstd, gm[1], bt[1]));
        pk.y = pk2bf(fmaf((z0v[2]-mu)*rstd, gm[2], bt[2]), fmaf((z0v[3]-mu)*rstd, gm[3], bt[3]));
        pk.z = pk2bf(fmaf((z0v[4]-mu)*rstd, gm[4], bt[4]), fmaf((z0v[5]-mu)*rstd, gm[5], bt[5]));
        pk.w = pk2bf(fmaf((z0v[6]-mu)*rstd, gm[6], bt[6]), fmaf((z0v[7]-mu)*rstd, gm[7], bt[7]));
        int slot = oc ^ ((rI >> 2) & 7);          // swizzle by batch = rI>>2
        *(uint4*)&SZb[rI * 64 + slot * 8] = pk;
    }
    __syncthreads();

    // phase 2, step 1: W bf16 words for 4 kc, two j-half passes (20-reg state)
    u32 bwst[4][4];                               // [kc][word]; word = m'/2 per jh
    #pragma unroll
    for (int jh = 0; jh < 2; ++jh) {
        float prh[20];
        {
            const float4* P4 = (const float4*)(P + ((size_t)i_w * 64 + jc_w * 8 + jh * 4) * 5);
            #pragma unroll
            for (int q = 0; q < 5; ++q) {
                float4 v = P4[q];
                prh[q*4+0] = v.x; prh[q*4+1] = v.y; prh[q*4+2] = v.z; prh[q*4+3] = v.w;
            }
        }
        float c0[20], c1[20], t2c[20];
        #pragma unroll
        for (int m = 0; m < 4; ++m) {
            #pragma unroll
            for (int g = 0; g < GG; ++g) {
                int idx = m * 5 + g;
                float pf = (float)((i_w * 64 + jc_w * 8 + jh * 4 + m) * 5 + g + 2);
                float inv = rcp_f(pf);
                c0[idx] = cos_rev(kf0 * inv);
                c1[idx] = cos_rev((kf0 + 1.0f) * inv);
                float ct = cos01(inv);
                t2c[idx] = ct + ct;
            }
        }
        #pragma unroll
        for (int kc = 0; kc < 4; ++kc) {
            if (kc >= 2) {
                #pragma unroll
                for (int x = 0; x < 20; ++x) {
                    float cn = fmaf(t2c[x], c1[x], -c0[x]);
                    c0[x] = c1[x]; c1[x] = cn;
                }
            }
            float av[4];
            #pragma unroll
            for (int m = 0; m < 4; ++m) {
                float a = 0.f;
                #pragma unroll
                for (int g = 0; g < GG; ++g) {
                    float ph = (kc == 0) ? c0[m * 5 + g] : c1[m * 5 + g];
                    a = fmaf(prh[m * 5 + g], ph, a);
                }
                av[m] = a;
            }
            bwst[kc][jh * 2 + 0] = pk2bf(av[0], av[1]);
            bwst[kc][jh * 2 + 1] = pk2bf(av[2], av[3]);
        }
    }

    // phase 2, step 2: T per kc via mfma_16x16x32 (no barriers; disjoint Ta)
    const int bcl = l & 7;
    #pragma unroll
    for (int kc = 0; kc < 4; ++kc) {
        union { uint4 u; s16x8 v; } bwu;
        bwu.u.x = bwst[kc][0]; bwu.u.y = bwst[kc][1];
        bwu.u.z = bwst[kc][2]; bwu.u.w = bwst[kc][3];
        int arow = bcl * 4 + kc;
        int slot = (h * 4 + (l >> 4)) ^ bcl;
        s16x8 az = *(const s16x8*)&SZb[arow * 64 + slot * 8];
        v4f zc = {0.f, 0.f, 0.f, 0.f};
        v4f d = __builtin_amdgcn_mfma_f32_16x16x32_bf16(az, bwu.v, zc, 0, 0, 0);
        if (l < 32) {
            int ii = i0 + (l & 15);
            int bb2 = (l >> 4) * 2;
            u32 base = (u32)((kc * 2 + h) * 64 + ii) * 5 + bb2;
            Ta32[base]     = pk2bf(d[0], d[1]);
            Ta32[base + 1] = pk2bf(d[2], d[3]);
        }
    }
    __syncthreads();

    const int ks = k0 >> 4;
    const int hi = (k0 >> 3) & 1;
    const int ofs = k0 & 4;                       // half-slot offset (4 bf16)

    // assembly: thread (w=b, l=i): V = T(h0)+T(h1)+Z0, write Vt half-slot
    {
        const u16* TaR = (const u16*)Ta32;
        float vk[4];
        #pragma unroll
        for (int kc = 0; kc < 4; ++kc)
            vk[kc] = bf2f(TaR[((kc * 2 + 0) * 64 + l) * 10 + w])
                   + bf2f(TaR[((kc * 2 + 1) * 64 + l) * 10 + w])
                   + Z0l[(w * 4 + kc) * 68 + l];
        uint2 pk2;
        pk2.x = pk2bf(vk[0], vk[1]);
        pk2.y = pk2bf(vk[2], vk[3]);
        size_t idx16 = ((size_t)(w * 2 + (l >> 5)) * 128 + ks) * 64 + (l & 31) + 32 * hi;
        *(uint2*)&Vt[idx16 * 8 + ofs] = pk2;
    }

    // Lt emission (this block's 4-k slice, all 512 threads; og = t)
    {
        uint2 pk2;
        pk2.x = pk2bf(lnv[0], lnv[1]);
        pk2.y = pk2bf(lnv[2], lnv[3]);
        size_t idx16 = ((size_t)(t >> 5) * 128 + ks) * 64 + (t & 31) + 32 * hi;
        *(uint2*)&Lt[idx16 * 8 + ofs] = pk2;
    }
}

// ---------------------------------------------------------------------------
// kB2 (R4-proven, byte-identical): out[b][o][i] direct. Grid 256 XCD-swizzled;
// block = 32o x 32i over full K=2048; 4 waves split K (512 each); double-
// buffered global_load_lds with counted vmcnt; LDS reduce; coalesced store.
// ---------------------------------------------------------------------------
__global__ __launch_bounds__(256, 2) void kB2(const u16* __restrict__ Lt,
                                              const u16* __restrict__ Vt,
                                              float* __restrict__ out) {
    __shared__ __align__(16) u16 LB[4][2][2][2048];  // [wave][buf][A/B] 4KB each
    const int t = threadIdx.x;
    const int l = t & 63, w = t >> 6;
    const int p = blockIdx.x;
    const int lg = (p & 7) * 32 + (p >> 3);   // bijective XCD swizzle (256%8==0)
    const int it = lg & 1, ot = (lg >> 1) & 15, b = lg >> 5;

    const u16* aG = Lt + (((size_t)ot * 128 + w * 32) * 64 + l) * 8;
    const u16* bG = Vt + (((size_t)(b * 2 + it) * 128 + w * 32) * 64 + l) * 8;

    v16f acc0 = {0,0,0,0,0,0,0,0,0,0,0,0,0,0,0,0};
    v16f acc1 = acc0;

#define STAGE(c, buf)                                                          \
    {                                                                          \
        _Pragma("unroll")                                                      \
        for (int ksl = 0; ksl < 4; ++ksl) {                                    \
            gload16(aG + ((c) * 4 + ksl) * 512, &LB[w][buf][0][ksl * 512]);    \
            gload16(bG + ((c) * 4 + ksl) * 512, &LB[w][buf][1][ksl * 512]);    \
        }                                                                      \
    }

    STAGE(0, 0);
    STAGE(1, 1);
    #pragma unroll
    for (int c = 0; c < 8; ++c) {
        if (c < 7) { asm volatile("s_waitcnt vmcnt(8)" ::: "memory"); }
        else       { asm volatile("s_waitcnt vmcnt(0)" ::: "memory"); }
        __builtin_amdgcn_sched_barrier(0);
        const int buf = c & 1;
        #pragma unroll
        for (int ksl = 0; ksl < 4; ++ksl) {
            s16x8 A = *(const s16x8*)&LB[w][buf][0][ksl * 512 + l * 8];
            s16x8 B = *(const s16x8*)&LB[w][buf][1][ksl * 512 + l * 8];
            if (ksl & 1) acc1 = __builtin_amdgcn_mfma_f32_32x32x16_bf16(A, B, acc1, 0, 0, 0);
            else         acc0 = __builtin_amdgcn_mfma_f32_32x32x16_bf16(A, B, acc0, 0, 0, 0);
        }
        asm volatile("s_waitcnt lgkmcnt(0)" ::: "memory");
        __builtin_amdgcn_sched_barrier(0);
        if (c + 2 < 8) STAGE(c + 2, buf);
    }
#undef STAGE

    // cross-wave K reduction in LDS (reuse LB), stride 17 = conflict-free
    __syncthreads();
    float* red = (float*)LB;
    {
        const int base = (w * 64 + l) * 17;
        #pragma unroll
        for (int r = 0; r < 16; ++r) red[base + r] = acc0[r] + acc1[r];
    }
    __syncthreads();
    {
        const int icol = t & 31;
        const int ob = (t >> 5) * 4;
        #pragma unroll
        for (int q = 0; q < 4; ++q) {
            const int orow = ob + q;
            const int hi = (orow >> 2) & 1;
            const int r = (orow & 3) | ((orow >> 3) << 2);
            const int lp = icol + 32 * hi;
            float s = red[(0 * 64 + lp) * 17 + r] + red[(1 * 64 + lp) * 17 + r]
                    + red[(2 * 64 + lp) * 17 + r] + red[(3 * 64 + lp) * 17 + r];
            out[((size_t)b * OSQ + ot * 32 + orow) * 64 + it * 32 + icol] = s;
        }
    }
}

extern "C" void kernel_launch(void* const* d_in, const int* in_sizes, int n_in,
                              void* d_out, int out_size, void* d_ws, size_t ws_size,
                              hipStream_t stream) {
    const float* seq   = (const float*)d_in[0];
    const float* Mm    = (const float*)d_in[1];
    const float* P     = (const float*)d_in[2];
    const float* Lnk   = (const float*)d_in[3];
    const float* gamma = (const float*)d_in[4];
    const float* beta  = (const float*)d_in[5];

    u16* Lt = (u16*)d_ws;                          // 512*2048 bf16 = 2 MB
    u16* Vt = (u16*)((char*)d_ws + (2u << 20));    // 8*64*2048 bf16 = 2 MB

    kF<<<512, 512, 0, stream>>>(seq, Mm, P, gamma, beta, Lnk, Lt, Vt);
    kB2<<<256, 256, 0, stream>>>(Lt, Vt, (float*)d_out);
}